// Round 15
// baseline (1057.571 us; speedup 1.0000x reference)
//
#include <hip/hip_runtime.h>
#include <hip/hip_bf16.h>
#include <math.h>

#define SEQ   2048
#define DM    1024
#define NH    16
#define DHD   64
#define FFD   4096
#define NV    32000

typedef __bf16 bf16x8 __attribute__((ext_vector_type(8)));
typedef float  f32x4  __attribute__((ext_vector_type(4)));

typedef __attribute__((address_space(1))) void* gas_ptr;
typedef __attribute__((address_space(3))) void* las_ptr;

static __device__ __forceinline__ void gload16(const void* g, void* l) {
  __builtin_amdgcn_global_load_lds((gas_ptr)g, (las_ptr)l, 16, 0, 0);
}

static __device__ __forceinline__ unsigned short f2bf(float f) {
  unsigned int x = __float_as_uint(f);
  return (unsigned short)((x + 0x7fffu + ((x >> 16) & 1u)) >> 16);
}

static __device__ __forceinline__ bf16x8 ld_frag(const unsigned short* p) {
  union { uint4 u; bf16x8 v; } r;
  r.u = *(const uint4*)p;
  return r.v;
}

// ---- transpose + f32->bf16 convert, batched over blockIdx.z layers ----
__global__ __launch_bounds__(256)
void k_transpose_bf16(const float* __restrict__ in, unsigned short* __restrict__ out,
                      int K, int N, size_t lstride) {
  in  += (size_t)blockIdx.z * lstride;
  out += (size_t)blockIdx.z * lstride;
  __shared__ float tl[64 * 65];
  const int bk = blockIdx.x * 64, bn = blockIdx.y * 64;
  const int t = threadIdx.x;
  const int tx = t & 15, ty = t >> 4;
#pragma unroll
  for (int i = 0; i < 4; ++i) {
    const int r = i * 16 + ty;
    float4 v = *(const float4*)&in[(size_t)(bk + r) * N + bn + tx * 4];
    tl[(tx * 4 + 0) * 65 + r] = v.x;
    tl[(tx * 4 + 1) * 65 + r] = v.y;
    tl[(tx * 4 + 2) * 65 + r] = v.z;
    tl[(tx * 4 + 3) * 65 + r] = v.w;
  }
  __syncthreads();
#pragma unroll
  for (int j = 0; j < 2; ++j) {
    const int f = j * 256 + t;
    const int n = f >> 3, kc = (f & 7) * 8;
    union { unsigned short u[8]; uint4 v; } pk;
#pragma unroll
    for (int e = 0; e < 8; ++e) pk.u[e] = f2bf(tl[n * 65 + kc + e]);
    *(uint4*)&out[(size_t)(bn + n) * K + bk + kc] = pk.v;
  }
}

// ---- per-head V transpose ----
__global__ __launch_bounds__(256)
void k_vT(const unsigned short* __restrict__ qkv, unsigned short* __restrict__ vT) {
  __shared__ unsigned short tile[32][33];
  const int bs = blockIdx.x * 32, bd = blockIdx.y * 32;
  const int tx = threadIdx.x & 31, ty = threadIdx.x >> 5;
#pragma unroll
  for (int r = ty; r < 32; r += 8)
    tile[r][tx] = qkv[(size_t)(bs + r) * (3 * DM) + 2 * DM + bd + tx];
  __syncthreads();
#pragma unroll
  for (int r = ty; r < 32; r += 8)
    vT[(size_t)(bd + r) * SEQ + bs + tx] = tile[tx][r];
}

// ---- embedding ----
__global__ __launch_bounds__(256)
void k_embed(const int* __restrict__ x, const float* __restrict__ tok,
             const float* __restrict__ pos, float* __restrict__ h) {
  const int row = blockIdx.x;
  const int d = threadIdx.x * 4;
  const int tk = x[row];
  float4 a = *(const float4*)(tok + (size_t)tk * DM + d);
  float4 p = *(const float4*)(pos + (size_t)row * DM + d);
  float4 o; o.x = a.x + p.x; o.y = a.y + p.y; o.z = a.z + p.z; o.w = a.w + p.w;
  *(float4*)(h + (size_t)row * DM + d) = o;
}

// ---- LayerNorm(in) -> bf16 out ----
__global__ __launch_bounds__(256)
void k_ln_bf16(const float* __restrict__ in, const float* __restrict__ g,
               const float* __restrict__ b, unsigned short* __restrict__ out) {
  const int row = blockIdx.x, t = threadIdx.x;
  float4 v = *(const float4*)(in + (size_t)row * DM + t * 4);
  float s = v.x + v.y + v.z + v.w;
  float q = v.x * v.x + v.y * v.y + v.z * v.z + v.w * v.w;
#pragma unroll
  for (int o = 32; o; o >>= 1) { s += __shfl_xor(s, o); q += __shfl_xor(q, o); }
  __shared__ float ls[4], lq[4];
  if ((t & 63) == 0) { ls[t >> 6] = s; lq[t >> 6] = q; }
  __syncthreads();
  s = ls[0] + ls[1] + ls[2] + ls[3];
  q = lq[0] + lq[1] + lq[2] + lq[3];
  const float mean = s * (1.f / DM);
  const float rstd = rsqrtf(q * (1.f / DM) - mean * mean + 1e-5f);
  float4 gg = *(const float4*)(g + t * 4);
  float4 bb = *(const float4*)(b + t * 4);
  ushort4 o4;
  o4.x = f2bf((v.x - mean) * rstd * gg.x + bb.x);
  o4.y = f2bf((v.y - mean) * rstd * gg.y + bb.y);
  o4.z = f2bf((v.z - mean) * rstd * gg.z + bb.z);
  o4.w = f2bf((v.w - mean) * rstd * gg.w + bb.w);
  *(ushort4*)(out + (size_t)row * DM + t * 4) = o4;
}

// ---- h += LN1(bo + sum4 slabs); out = bf16(LN2(h)) ----
__global__ __launch_bounds__(256)
void k_addslab_ln_ln(float* __restrict__ h, const float* __restrict__ sl,
                     const float* __restrict__ bo,
                     const float* __restrict__ g1, const float* __restrict__ b1,
                     const float* __restrict__ g2, const float* __restrict__ b2,
                     unsigned short* __restrict__ out) {
  const int row = blockIdx.x, t = threadIdx.x;
  __shared__ float ls[4], lq[4], ls2[4], lq2[4];
  const size_t idx = (size_t)row * DM + t * 4;
  float4 v = *(const float4*)(bo + t * 4);
#pragma unroll
  for (int c = 0; c < 4; ++c) {
    float4 p = *(const float4*)(sl + (size_t)c * SEQ * DM + idx);
    v.x += p.x; v.y += p.y; v.z += p.z; v.w += p.w;
  }
  float s = v.x + v.y + v.z + v.w;
  float q = v.x * v.x + v.y * v.y + v.z * v.z + v.w * v.w;
#pragma unroll
  for (int o = 32; o; o >>= 1) { s += __shfl_xor(s, o); q += __shfl_xor(q, o); }
  if ((t & 63) == 0) { ls[t >> 6] = s; lq[t >> 6] = q; }
  __syncthreads();
  s = ls[0] + ls[1] + ls[2] + ls[3];
  q = lq[0] + lq[1] + lq[2] + lq[3];
  const float mean = s * (1.f / DM);
  const float rstd = rsqrtf(q * (1.f / DM) - mean * mean + 1e-5f);
  float4 gg = *(const float4*)(g1 + t * 4);
  float4 bb = *(const float4*)(b1 + t * 4);
  float4 hv = *(const float4*)(h + idx);
  hv.x += (v.x - mean) * rstd * gg.x + bb.x;
  hv.y += (v.y - mean) * rstd * gg.y + bb.y;
  hv.z += (v.z - mean) * rstd * gg.z + bb.z;
  hv.w += (v.w - mean) * rstd * gg.w + bb.w;
  *(float4*)(h + idx) = hv;
  float s2 = hv.x + hv.y + hv.z + hv.w;
  float q2 = hv.x * hv.x + hv.y * hv.y + hv.z * hv.z + hv.w * hv.w;
#pragma unroll
  for (int o = 32; o; o >>= 1) { s2 += __shfl_xor(s2, o); q2 += __shfl_xor(q2, o); }
  if ((t & 63) == 0) { ls2[t >> 6] = s2; lq2[t >> 6] = q2; }
  __syncthreads();
  s2 = ls2[0] + ls2[1] + ls2[2] + ls2[3];
  q2 = lq2[0] + lq2[1] + lq2[2] + lq2[3];
  const float mean2 = s2 * (1.f / DM);
  const float rstd2 = rsqrtf(q2 * (1.f / DM) - mean2 * mean2 + 1e-5f);
  float4 g2v = *(const float4*)(g2 + t * 4);
  float4 b2v = *(const float4*)(b2 + t * 4);
  ushort4 o4;
  o4.x = f2bf((hv.x - mean2) * rstd2 * g2v.x + b2v.x);
  o4.y = f2bf((hv.y - mean2) * rstd2 * g2v.y + b2v.y);
  o4.z = f2bf((hv.z - mean2) * rstd2 * g2v.z + b2v.z);
  o4.w = f2bf((hv.w - mean2) * rstd2 * g2v.w + b2v.w);
  *(ushort4*)(out + (size_t)row * DM + t * 4) = o4;
}

// ---- h += b2 + sum4 slabs; ybf = bf16(LN(h, g, b)) ----
__global__ __launch_bounds__(256)
void k_redadd_ln(float* __restrict__ h, const float* __restrict__ sl,
                 const float* __restrict__ b2,
                 const float* __restrict__ g, const float* __restrict__ b,
                 unsigned short* __restrict__ out) {
  const int row = blockIdx.x, t = threadIdx.x;
  __shared__ float ls[4], lq[4];
  const size_t idx = (size_t)row * DM + t * 4;
  float4 hv = *(const float4*)(h + idx);
  float4 bb = *(const float4*)(b2 + t * 4);
  hv.x += bb.x; hv.y += bb.y; hv.z += bb.z; hv.w += bb.w;
#pragma unroll
  for (int c = 0; c < 4; ++c) {
    float4 p = *(const float4*)(sl + (size_t)c * SEQ * DM + idx);
    hv.x += p.x; hv.y += p.y; hv.z += p.z; hv.w += p.w;
  }
  *(float4*)(h + idx) = hv;
  float s = hv.x + hv.y + hv.z + hv.w;
  float q = hv.x * hv.x + hv.y * hv.y + hv.z * hv.z + hv.w * hv.w;
#pragma unroll
  for (int o = 32; o; o >>= 1) { s += __shfl_xor(s, o); q += __shfl_xor(q, o); }
  if ((t & 63) == 0) { ls[t >> 6] = s; lq[t >> 6] = q; }
  __syncthreads();
  s = ls[0] + ls[1] + ls[2] + ls[3];
  q = lq[0] + lq[1] + lq[2] + lq[3];
  const float mean = s * (1.f / DM);
  const float rstd = rsqrtf(q * (1.f / DM) - mean * mean + 1e-5f);
  float4 gg = *(const float4*)(g + t * 4);
  float4 b1 = *(const float4*)(b + t * 4);
  ushort4 o4;
  o4.x = f2bf((hv.x - mean) * rstd * gg.x + b1.x);
  o4.y = f2bf((hv.y - mean) * rstd * gg.y + b1.y);
  o4.z = f2bf((hv.z - mean) * rstd * gg.z + b1.z);
  o4.w = f2bf((hv.w - mean) * rstd * gg.w + b1.w);
  *(ushort4*)(out + (size_t)row * DM + t * 4) = o4;
}

// ---- GEMM v4: 128x128, 4 waves, BK=32 dbuf (32KB LDS), 3 blocks/CU ----
// EPI: 0 bf16; 1 +bias f32; 2 +bias gelu bf16; 4 slab f32 (blockIdx.y)
template<int EPI>
__global__ __launch_bounds__(256)
void k_gemm4(const unsigned short* __restrict__ A, const unsigned short* __restrict__ Bt,
             float* __restrict__ outF, unsigned short* __restrict__ outB,
             const float* __restrict__ bias, int N, int K, int kLen, int gm) {
  __shared__ __align__(16) unsigned short L[16384];
  const int nwg = gridDim.x, pid = blockIdx.x;
  const int qq = nwg >> 3, rr = nwg & 7;
  const int xcd = pid & 7, lo = pid >> 3;
  const int wg = ((xcd < rr) ? xcd * (qq + 1) : rr * (qq + 1) + (xcd - rr) * qq) + lo;
  const int bm = wg % gm, bn = wg / gm;
  const int kOff = blockIdx.y * kLen;
  const int t = threadIdx.x, lane = t & 63, w = t >> 6;
  const int wm = w >> 1, wn = w & 1, lr = lane & 15, lg = lane >> 4;

  const unsigned short* gA[2]; const unsigned short* gB[2];
  unsigned short* lA[2]; unsigned short* lB[2];
#pragma unroll
  for (int j = 0; j < 2; ++j) {
    const int f = j * 256 + t;
    const int row = f >> 2;
    const int c = (f & 3) ^ ((row >> 1) & 3);
    gA[j] = A  + (size_t)(bm * 128 + row) * K + kOff + c * 8;
    gB[j] = Bt + (size_t)(bn * 128 + row) * K + kOff + c * 8;
    lA[j] = L + f * 8;
    lB[j] = L + 4096 + f * 8;
  }
  auto stage = [&](int k0, int cb) {
#pragma unroll
    for (int j = 0; j < 2; ++j) gload16(gA[j] + k0, lA[j] + cb * 8192);
#pragma unroll
    for (int j = 0; j < 2; ++j) gload16(gB[j] + k0, lB[j] + cb * 8192);
  };

  int offA[4], offB[4];
#pragma unroll
  for (int mt = 0; mt < 4; ++mt) {
    const int rowA = wm * 64 + mt * 16 + lr;
    offA[mt] = rowA * 32 + ((lg ^ ((rowA >> 1) & 3)) << 3);
    const int rowB = wn * 64 + mt * 16 + lr;
    offB[mt] = 4096 + rowB * 32 + ((lg ^ ((rowB >> 1) & 3)) << 3);
  }

  f32x4 acc[4][4];
#pragma unroll
  for (int i = 0; i < 4; ++i)
#pragma unroll
    for (int j = 0; j < 4; ++j) acc[i][j] = (f32x4){0.f, 0.f, 0.f, 0.f};

  const int NT = kLen >> 5;
  stage(0, 0);
  stage(32, 1);

  for (int tt = 0; tt < NT; ++tt) {
    const int cb = tt & 1;
    if (tt + 1 < NT) asm volatile("s_waitcnt vmcnt(4)" ::: "memory");
    else             asm volatile("s_waitcnt vmcnt(0)" ::: "memory");
    __builtin_amdgcn_s_barrier();
    const unsigned short* buf = L + cb * 8192;
    bf16x8 af[4], bfr[4];
#pragma unroll
    for (int mt = 0; mt < 4; ++mt) {
      af[mt]  = ld_frag(buf + offA[mt]);
      bfr[mt] = ld_frag(buf + offB[mt]);
    }
    __builtin_amdgcn_s_setprio(1);
#pragma unroll
    for (int mt = 0; mt < 4; ++mt)
#pragma unroll
      for (int nt = 0; nt < 4; ++nt)
        acc[mt][nt] = __builtin_amdgcn_mfma_f32_16x16x32_bf16(af[mt], bfr[nt], acc[mt][nt], 0, 0, 0);
    __builtin_amdgcn_s_setprio(0);
    __builtin_amdgcn_s_barrier();
    if (tt + 2 < NT) stage((tt + 2) << 5, cb);
  }

  const int rbase = bm * 128 + wm * 64;
  const int cbase = bn * 128 + wn * 64;
  float* outP = outF;
  if constexpr (EPI == 4) outP = outF + (size_t)blockIdx.y * SEQ * N;
#pragma unroll
  for (int mt = 0; mt < 4; ++mt) {
#pragma unroll
    for (int nt = 0; nt < 4; ++nt) {
      const int col = cbase + nt * 16 + lr;
      float bv = 0.f;
      if constexpr (EPI == 1 || EPI == 2) bv = bias[col];
#pragma unroll
      for (int r = 0; r < 4; ++r) {
        const int row = rbase + mt * 16 + lg * 4 + r;
        float v = acc[mt][nt][r] + bv;
        if constexpr (EPI == 2) v = 0.5f * v * (1.f + erff(v * 0.70710678118f));
        if constexpr (EPI == 0 || EPI == 2) outB[(size_t)row * N + col] = f2bf(v);
        else                                outP[(size_t)row * N + col] = v;
      }
    }
  }
}

// ---- fused causal ReLA attention: balanced q-strip pairs, dbuf K/V ----
// Block (jb,hd) computes strips qbA=jb, qbB=31-jb over one kv loop (33 tiles).
// K/V double-buffered, counted vmcnt(4) + raw s_barrier in the loop.
__global__ __launch_bounds__(256)
void k_rela_attn(const unsigned short* __restrict__ qkv,
                 const unsigned short* __restrict__ vT,
                 unsigned short* __restrict__ obf) {
  const int jb = blockIdx.x;      // 0..15
  const int hd = blockIdx.y;      // 0..15
  const int qbA = jb, qbB = 31 - jb;
  const int t = threadIdx.x, lane = t & 63, w = t >> 6;
  const int lr = lane & 15, lg = lane >> 4;

  __shared__ __align__(16) unsigned short Qs[128 * 64];
  __shared__ __align__(16) unsigned short Ks[2][64 * 64];
  __shared__ __align__(16) unsigned short Vs[2][64 * 64];
  __shared__ __align__(16) unsigned short Ps[4][16 * 72];

  const int sr8 = lane >> 3;
  const int sch = ((lane & 7) ^ sr8) << 3;

#pragma unroll
  for (int qi = 0; qi < 4; ++qi) {
    const int i = w * 4 + qi;
    const int rl = i * 8 + sr8;
    const int grow = (rl < 64) ? (qbA * 64 + rl) : (qbB * 64 + rl - 64);
    gload16(qkv + (size_t)grow * (3 * DM) + hd * DHD + sch, Qs + i * 512);
  }
  __syncthreads();

  bf16x8 qfA[2], qfB[2];
#pragma unroll
  for (int ks = 0; ks < 2; ++ks) {
    const int rowA = w * 16 + lr;
    qfA[ks] = ld_frag(&Qs[rowA * 64 + (((ks * 4 + lg) ^ (lr & 7)) << 3)]);
    const int rowB = 64 + w * 16 + lr;
    qfB[ks] = ld_frag(&Qs[rowB * 64 + (((ks * 4 + lg) ^ (lr & 7)) << 3)]);
  }

  const f32x4 zero = {0.f, 0.f, 0.f, 0.f};
  f32x4 accA[4], accB[4];
#pragma unroll
  for (int nt = 0; nt < 4; ++nt) { accA[nt] = zero; accB[nt] = zero; }

  auto stage = [&](int kt, int cb) {
#pragma unroll
    for (int qi = 0; qi < 2; ++qi) {
      const int i = w * 2 + qi;
      const int rl = i * 8 + sr8;
      gload16(qkv + (size_t)(kt * 64 + rl) * (3 * DM) + DM + hd * DHD + sch, &Ks[cb][i * 512]);
      gload16(vT + (size_t)(hd * DHD + rl) * SEQ + kt * 64 + sch, &Vs[cb][i * 512]);
    }
  };

  auto tile_step = [&](const bf16x8* qf, f32x4* acc, int qb, int kt, int cb) {
    f32x4 sv[4];
#pragma unroll
    for (int nt = 0; nt < 4; ++nt) sv[nt] = zero;
#pragma unroll
    for (int ks = 0; ks < 2; ++ks)
#pragma unroll
      for (int nt = 0; nt < 4; ++nt) {
        bf16x8 kf = ld_frag(&Ks[cb][(nt * 16 + lr) * 64 + (((ks * 4 + lg) ^ (lr & 7)) << 3)]);
        sv[nt] = __builtin_amdgcn_mfma_f32_16x16x32_bf16(qf[ks], kf, sv[nt], 0, 0, 0);
      }
    const bool diag = (kt == qb);
#pragma unroll
    for (int nt = 0; nt < 4; ++nt)
#pragma unroll
      for (int r = 0; r < 4; ++r) {
        float v = fmaxf(sv[nt][r], 0.f) * 0.125f;
        if (diag) {
          const int ii = w * 16 + lg * 4 + r;
          const int jj = nt * 16 + lr;
          if (jj > ii) v = 0.f;
        }
        Ps[w][(lg * 4 + r) * 72 + nt * 16 + lr] = f2bf(v);
      }
#pragma unroll
    for (int ks = 0; ks < 2; ++ks) {
      bf16x8 pf = ld_frag(&Ps[w][lr * 72 + ks * 32 + lg * 8]);
#pragma unroll
      for (int nt = 0; nt < 4; ++nt) {
        bf16x8 vf = ld_frag(&Vs[cb][(nt * 16 + lr) * 64 + (((ks * 4 + lg) ^ (lr & 7)) << 3)]);
        acc[nt] = __builtin_amdgcn_mfma_f32_16x16x32_bf16(pf, vf, acc[nt], 0, 0, 0);
      }
    }
  };

  stage(0, 0);
  for (int kt = 0; kt <= qbB; ++kt) {
    const int cb = kt & 1;
    if (kt < qbB) {
      stage(kt + 1, cb ^ 1);
      asm volatile("s_waitcnt vmcnt(4)" ::: "memory");
    } else {
      asm volatile("s_waitcnt vmcnt(0)" ::: "memory");
    }
    __builtin_amdgcn_s_barrier();
    tile_step(qfB, accB, qbB, kt, cb);
    if (kt <= qbA) tile_step(qfA, accA, qbA, kt, cb);
    __builtin_amdgcn_s_barrier();
  }

#pragma unroll
  for (int nt = 0; nt < 4; ++nt)
#pragma unroll
    for (int r = 0; r < 4; ++r) {
      const int col = hd * DHD + nt * 16 + lr;
      const int rowA = qbA * 64 + w * 16 + lg * 4 + r;
      obf[(size_t)rowA * DM + col] = f2bf(accA[nt][r]);
      const int rowB = qbB * 64 + w * 16 + lg * 4 + r;
      obf[(size_t)rowB * DM + col] = f2bf(accB[nt][r]);
    }
}

extern "C" void kernel_launch(void* const* d_in, const int* in_sizes, int n_in,
                              void* d_out, int out_size, void* d_ws, size_t ws_size,
                              hipStream_t stream) {
  const int*   x       = (const int*)d_in[0];
  const float* tok_emb = (const float*)d_in[1];
  const float* pos_emb = (const float*)d_in[2];
  const float* attn_ng = (const float*)d_in[3];
  const float* attn_nb = (const float*)d_in[4];
  const float* wqkv    = (const float*)d_in[5];
  const float* wo      = (const float*)d_in[6];
  const float* bo      = (const float*)d_in[7];
  const float* out_ng  = (const float*)d_in[8];
  const float* out_nb  = (const float*)d_in[9];
  const float* ff_ng   = (const float*)d_in[10];
  const float* ff_nb   = (const float*)d_in[11];
  const float* w1      = (const float*)d_in[12];
  const float* b1      = (const float*)d_in[13];
  const float* w2      = (const float*)d_in[14];
  const float* b2      = (const float*)d_in[15];
  const float* fin_g   = (const float*)d_in[16];
  const float* fin_b   = (const float*)d_in[17];
  const float* w_logit = (const float*)d_in[18];
  const float* b_logit = (const float*)d_in[19];
  float* out = (float*)d_out;

  char* ws = (char*)d_ws;
  size_t off = 0;
  auto alloc = [&](size_t bytes) -> void* {
    void* p = ws + off;
    off = (off + bytes + 255) & ~(size_t)255;
    return p;
  };
  unsigned short* wqkvT = (unsigned short*)alloc(4ull * 3072 * 1024 * 2);
  unsigned short* woT   = (unsigned short*)alloc(4ull * 1024 * 1024 * 2);
  unsigned short* w1T   = (unsigned short*)alloc(4ull * 4096 * 1024 * 2);
  unsigned short* w2T   = (unsigned short*)alloc(4ull * 1024 * 4096 * 2);
  unsigned short* wlogT = (unsigned short*)alloc((size_t)NV * 1024 * 2);
  float*          h     = (float*)alloc((size_t)SEQ * DM * 4);
  unsigned short* ybf   = (unsigned short*)alloc((size_t)SEQ * DM * 2);
  unsigned short* qkvbf = (unsigned short*)alloc((size_t)SEQ * 3 * DM * 2);
  unsigned short* vTb   = (unsigned short*)alloc((size_t)DM * SEQ * 2);
  unsigned short* obf   = (unsigned short*)alloc((size_t)SEQ * DM * 2);
  unsigned short* ffbf  = (unsigned short*)alloc((size_t)SEQ * FFD * 2);
  float*          slabs = (float*)alloc(4ull * SEQ * DM * 4);
  (void)ws_size; (void)in_sizes; (void)n_in; (void)out_size;

  const dim3 B(256);

  k_transpose_bf16<<<dim3(16, 48, 4), B, 0, stream>>>(wqkv, wqkvT, 1024, 3072, (size_t)1024 * 3072);
  k_transpose_bf16<<<dim3(16, 16, 4), B, 0, stream>>>(wo, woT, 1024, 1024, (size_t)1024 * 1024);
  k_transpose_bf16<<<dim3(16, 64, 4), B, 0, stream>>>(w1, w1T, 1024, 4096, (size_t)1024 * 4096);
  k_transpose_bf16<<<dim3(64, 16, 4), B, 0, stream>>>(w2, w2T, 4096, 1024, (size_t)4096 * 1024);
  k_transpose_bf16<<<dim3(16, 500, 1), B, 0, stream>>>(w_logit, wlogT, 1024, NV, 0);

  k_embed<<<SEQ, B, 0, stream>>>(x, tok_emb, pos_emb, h);
  k_ln_bf16<<<SEQ, B, 0, stream>>>(h, attn_ng, attn_nb, ybf);

  for (int l = 0; l < 4; ++l) {
    k_gemm4<0><<<dim3(384), B, 0, stream>>>(
        ybf, wqkvT + (size_t)l * 3072 * 1024, nullptr, qkvbf, nullptr, 3072, 1024, 1024, 16);
    k_vT<<<dim3(SEQ / 32, DM / 32), B, 0, stream>>>(qkvbf, vTb);
    k_rela_attn<<<dim3(16, NH), B, 0, stream>>>(qkvbf, vTb, obf);
    k_gemm4<4><<<dim3(128, 4), B, 0, stream>>>(
        obf, woT + (size_t)l * 1024 * 1024, slabs, nullptr, nullptr, 1024, 1024, 256, 16);
    k_addslab_ln_ln<<<SEQ, B, 0, stream>>>(h, slabs, bo + l * DM,
                                           out_ng + l * DM, out_nb + l * DM,
                                           ff_ng + l * DM, ff_nb + l * DM, ybf);
    k_gemm4<2><<<dim3(512), B, 0, stream>>>(
        ybf, w1T + (size_t)l * 4096 * 1024, nullptr, ffbf, b1 + l * FFD, 4096, 1024, 1024, 16);
    k_gemm4<4><<<dim3(128, 4), B, 0, stream>>>(
        ffbf, w2T + (size_t)l * 1024 * 4096, slabs, nullptr, nullptr, 1024, 4096, 1024, 16);
    const float* ng = (l < 3) ? (attn_ng + (l + 1) * DM) : fin_g;
    const float* nb = (l < 3) ? (attn_nb + (l + 1) * DM) : fin_b;
    k_redadd_ln<<<SEQ, B, 0, stream>>>(h, slabs, b2 + l * DM, ng, nb, ybf);
  }

  k_gemm4<1><<<dim3(4000), B, 0, stream>>>(ybf, wlogT, out, nullptr, b_logit, NV, 1024, 1024, 16);
}

// Round 16
// 1020.360 us; speedup vs baseline: 1.0365x; 1.0365x over previous
//
#include <hip/hip_runtime.h>
#include <hip/hip_bf16.h>
#include <math.h>

#define SEQ   2048
#define DM    1024
#define NH    16
#define DHD   64
#define FFD   4096
#define NV    32000

typedef __bf16 bf16x8 __attribute__((ext_vector_type(8)));
typedef float  f32x4  __attribute__((ext_vector_type(4)));

typedef __attribute__((address_space(1))) void* gas_ptr;
typedef __attribute__((address_space(3))) void* las_ptr;

static __device__ __forceinline__ void gload16(const void* g, void* l) {
  __builtin_amdgcn_global_load_lds((gas_ptr)g, (las_ptr)l, 16, 0, 0);
}

static __device__ __forceinline__ unsigned short f2bf(float f) {
  unsigned int x = __float_as_uint(f);
  return (unsigned short)((x + 0x7fffu + ((x >> 16) & 1u)) >> 16);
}

static __device__ __forceinline__ bf16x8 ld_frag(const unsigned short* p) {
  union { uint4 u; bf16x8 v; } r;
  r.u = *(const uint4*)p;
  return r.v;
}

// ---- transpose + f32->bf16 convert, batched over blockIdx.z layers ----
__global__ __launch_bounds__(256)
void k_transpose_bf16(const float* __restrict__ in, unsigned short* __restrict__ out,
                      int K, int N, size_t lstride) {
  in  += (size_t)blockIdx.z * lstride;
  out += (size_t)blockIdx.z * lstride;
  __shared__ float tl[64 * 65];
  const int bk = blockIdx.x * 64, bn = blockIdx.y * 64;
  const int t = threadIdx.x;
  const int tx = t & 15, ty = t >> 4;
#pragma unroll
  for (int i = 0; i < 4; ++i) {
    const int r = i * 16 + ty;
    float4 v = *(const float4*)&in[(size_t)(bk + r) * N + bn + tx * 4];
    tl[(tx * 4 + 0) * 65 + r] = v.x;
    tl[(tx * 4 + 1) * 65 + r] = v.y;
    tl[(tx * 4 + 2) * 65 + r] = v.z;
    tl[(tx * 4 + 3) * 65 + r] = v.w;
  }
  __syncthreads();
#pragma unroll
  for (int j = 0; j < 2; ++j) {
    const int f = j * 256 + t;
    const int n = f >> 3, kc = (f & 7) * 8;
    union { unsigned short u[8]; uint4 v; } pk;
#pragma unroll
    for (int e = 0; e < 8; ++e) pk.u[e] = f2bf(tl[n * 65 + kc + e]);
    *(uint4*)&out[(size_t)(bn + n) * K + bk + kc] = pk.v;
  }
}

// ---- embedding ----
__global__ __launch_bounds__(256)
void k_embed(const int* __restrict__ x, const float* __restrict__ tok,
             const float* __restrict__ pos, float* __restrict__ h) {
  const int row = blockIdx.x;
  const int d = threadIdx.x * 4;
  const int tk = x[row];
  float4 a = *(const float4*)(tok + (size_t)tk * DM + d);
  float4 p = *(const float4*)(pos + (size_t)row * DM + d);
  float4 o; o.x = a.x + p.x; o.y = a.y + p.y; o.z = a.z + p.z; o.w = a.w + p.w;
  *(float4*)(h + (size_t)row * DM + d) = o;
}

// ---- LayerNorm(in) -> bf16 out ----
__global__ __launch_bounds__(256)
void k_ln_bf16(const float* __restrict__ in, const float* __restrict__ g,
               const float* __restrict__ b, unsigned short* __restrict__ out) {
  const int row = blockIdx.x, t = threadIdx.x;
  float4 v = *(const float4*)(in + (size_t)row * DM + t * 4);
  float s = v.x + v.y + v.z + v.w;
  float q = v.x * v.x + v.y * v.y + v.z * v.z + v.w * v.w;
#pragma unroll
  for (int o = 32; o; o >>= 1) { s += __shfl_xor(s, o); q += __shfl_xor(q, o); }
  __shared__ float ls[4], lq[4];
  if ((t & 63) == 0) { ls[t >> 6] = s; lq[t >> 6] = q; }
  __syncthreads();
  s = ls[0] + ls[1] + ls[2] + ls[3];
  q = lq[0] + lq[1] + lq[2] + lq[3];
  const float mean = s * (1.f / DM);
  const float rstd = rsqrtf(q * (1.f / DM) - mean * mean + 1e-5f);
  float4 gg = *(const float4*)(g + t * 4);
  float4 bb = *(const float4*)(b + t * 4);
  ushort4 o4;
  o4.x = f2bf((v.x - mean) * rstd * gg.x + bb.x);
  o4.y = f2bf((v.y - mean) * rstd * gg.y + bb.y);
  o4.z = f2bf((v.z - mean) * rstd * gg.z + bb.z);
  o4.w = f2bf((v.w - mean) * rstd * gg.w + bb.w);
  *(ushort4*)(out + (size_t)row * DM + t * 4) = o4;
}

// ---- obf = bf16(slab0 + slab1) ----
__global__ __launch_bounds__(256)
void k_ored(const float* __restrict__ sl, unsigned short* __restrict__ obf) {
  const int row = blockIdx.x, t = threadIdx.x;
  const size_t idx = (size_t)row * DM + t * 4;
  float4 a = *(const float4*)(sl + idx);
  float4 b = *(const float4*)(sl + (size_t)SEQ * DM + idx);
  ushort4 o4;
  o4.x = f2bf(a.x + b.x);
  o4.y = f2bf(a.y + b.y);
  o4.z = f2bf(a.z + b.z);
  o4.w = f2bf(a.w + b.w);
  *(ushort4*)(obf + idx) = o4;
}

// ---- h += LN1(bo + sum4 slabs); out = bf16(LN2(h)) ----
__global__ __launch_bounds__(256)
void k_addslab_ln_ln(float* __restrict__ h, const float* __restrict__ sl,
                     const float* __restrict__ bo,
                     const float* __restrict__ g1, const float* __restrict__ b1,
                     const float* __restrict__ g2, const float* __restrict__ b2,
                     unsigned short* __restrict__ out) {
  const int row = blockIdx.x, t = threadIdx.x;
  __shared__ float ls[4], lq[4], ls2[4], lq2[4];
  const size_t idx = (size_t)row * DM + t * 4;
  float4 v = *(const float4*)(bo + t * 4);
#pragma unroll
  for (int c = 0; c < 4; ++c) {
    float4 p = *(const float4*)(sl + (size_t)c * SEQ * DM + idx);
    v.x += p.x; v.y += p.y; v.z += p.z; v.w += p.w;
  }
  float s = v.x + v.y + v.z + v.w;
  float q = v.x * v.x + v.y * v.y + v.z * v.z + v.w * v.w;
#pragma unroll
  for (int o = 32; o; o >>= 1) { s += __shfl_xor(s, o); q += __shfl_xor(q, o); }
  if ((t & 63) == 0) { ls[t >> 6] = s; lq[t >> 6] = q; }
  __syncthreads();
  s = ls[0] + ls[1] + ls[2] + ls[3];
  q = lq[0] + lq[1] + lq[2] + lq[3];
  const float mean = s * (1.f / DM);
  const float rstd = rsqrtf(q * (1.f / DM) - mean * mean + 1e-5f);
  float4 gg = *(const float4*)(g1 + t * 4);
  float4 bb = *(const float4*)(b1 + t * 4);
  float4 hv = *(const float4*)(h + idx);
  hv.x += (v.x - mean) * rstd * gg.x + bb.x;
  hv.y += (v.y - mean) * rstd * gg.y + bb.y;
  hv.z += (v.z - mean) * rstd * gg.z + bb.z;
  hv.w += (v.w - mean) * rstd * gg.w + bb.w;
  *(float4*)(h + idx) = hv;
  float s2 = hv.x + hv.y + hv.z + hv.w;
  float q2 = hv.x * hv.x + hv.y * hv.y + hv.z * hv.z + hv.w * hv.w;
#pragma unroll
  for (int o = 32; o; o >>= 1) { s2 += __shfl_xor(s2, o); q2 += __shfl_xor(q2, o); }
  if ((t & 63) == 0) { ls2[t >> 6] = s2; lq2[t >> 6] = q2; }
  __syncthreads();
  s2 = ls2[0] + ls2[1] + ls2[2] + ls2[3];
  q2 = lq2[0] + lq2[1] + lq2[2] + lq2[3];
  const float mean2 = s2 * (1.f / DM);
  const float rstd2 = rsqrtf(q2 * (1.f / DM) - mean2 * mean2 + 1e-5f);
  float4 g2v = *(const float4*)(g2 + t * 4);
  float4 b2v = *(const float4*)(b2 + t * 4);
  ushort4 o4;
  o4.x = f2bf((hv.x - mean2) * rstd2 * g2v.x + b2v.x);
  o4.y = f2bf((hv.y - mean2) * rstd2 * g2v.y + b2v.y);
  o4.z = f2bf((hv.z - mean2) * rstd2 * g2v.z + b2v.z);
  o4.w = f2bf((hv.w - mean2) * rstd2 * g2v.w + b2v.w);
  *(ushort4*)(out + (size_t)row * DM + t * 4) = o4;
}

// ---- h += b2 + sum4 slabs; ybf = bf16(LN(h, g, b)) ----
__global__ __launch_bounds__(256)
void k_redadd_ln(float* __restrict__ h, const float* __restrict__ sl,
                 const float* __restrict__ b2,
                 const float* __restrict__ g, const float* __restrict__ b,
                 unsigned short* __restrict__ out) {
  const int row = blockIdx.x, t = threadIdx.x;
  __shared__ float ls[4], lq[4];
  const size_t idx = (size_t)row * DM + t * 4;
  float4 hv = *(const float4*)(h + idx);
  float4 bb = *(const float4*)(b2 + t * 4);
  hv.x += bb.x; hv.y += bb.y; hv.z += bb.z; hv.w += bb.w;
#pragma unroll
  for (int c = 0; c < 4; ++c) {
    float4 p = *(const float4*)(sl + (size_t)c * SEQ * DM + idx);
    hv.x += p.x; hv.y += p.y; hv.z += p.z; hv.w += p.w;
  }
  *(float4*)(h + idx) = hv;
  float s = hv.x + hv.y + hv.z + hv.w;
  float q = hv.x * hv.x + hv.y * hv.y + hv.z * hv.z + hv.w * hv.w;
#pragma unroll
  for (int o = 32; o; o >>= 1) { s += __shfl_xor(s, o); q += __shfl_xor(q, o); }
  if ((t & 63) == 0) { ls[t >> 6] = s; lq[t >> 6] = q; }
  __syncthreads();
  s = ls[0] + ls[1] + ls[2] + ls[3];
  q = lq[0] + lq[1] + lq[2] + lq[3];
  const float mean = s * (1.f / DM);
  const float rstd = rsqrtf(q * (1.f / DM) - mean * mean + 1e-5f);
  float4 gg = *(const float4*)(g + t * 4);
  float4 b1 = *(const float4*)(b + t * 4);
  ushort4 o4;
  o4.x = f2bf((hv.x - mean) * rstd * gg.x + b1.x);
  o4.y = f2bf((hv.y - mean) * rstd * gg.y + b1.y);
  o4.z = f2bf((hv.z - mean) * rstd * gg.z + b1.z);
  o4.w = f2bf((hv.w - mean) * rstd * gg.w + b1.w);
  *(ushort4*)(out + (size_t)row * DM + t * 4) = o4;
}

// ---- GEMM v4: 128x128, 4 waves, BK=32 dbuf (32KB LDS), 3 blocks/CU ----
// EPI: 0 bf16; 1 +bias f32; 2 +bias gelu bf16; 4 slab f32 (blockIdx.y);
//      5 qkv: cols<2048 -> bf16 outB; cols>=2048 (V) -> transposed vT[d][s]
template<int EPI>
__global__ __launch_bounds__(256)
void k_gemm4(const unsigned short* __restrict__ A, const unsigned short* __restrict__ Bt,
             float* __restrict__ outF, unsigned short* __restrict__ outB,
             const float* __restrict__ bias, int N, int K, int kLen, int gm) {
  __shared__ __align__(16) unsigned short L[16384];
  const int nwg = gridDim.x, pid = blockIdx.x;
  const int qq = nwg >> 3, rr = nwg & 7;
  const int xcd = pid & 7, lo = pid >> 3;
  const int wg = ((xcd < rr) ? xcd * (qq + 1) : rr * (qq + 1) + (xcd - rr) * qq) + lo;
  const int bm = wg % gm, bn = wg / gm;
  const int kOff = blockIdx.y * kLen;
  const int t = threadIdx.x, lane = t & 63, w = t >> 6;
  const int wm = w >> 1, wn = w & 1, lr = lane & 15, lg = lane >> 4;

  const unsigned short* gA[2]; const unsigned short* gB[2];
  unsigned short* lA[2]; unsigned short* lB[2];
#pragma unroll
  for (int j = 0; j < 2; ++j) {
    const int f = j * 256 + t;
    const int row = f >> 2;
    const int c = (f & 3) ^ ((row >> 1) & 3);
    gA[j] = A  + (size_t)(bm * 128 + row) * K + kOff + c * 8;
    gB[j] = Bt + (size_t)(bn * 128 + row) * K + kOff + c * 8;
    lA[j] = L + f * 8;
    lB[j] = L + 4096 + f * 8;
  }
  auto stage = [&](int k0, int cb) {
#pragma unroll
    for (int j = 0; j < 2; ++j) gload16(gA[j] + k0, lA[j] + cb * 8192);
#pragma unroll
    for (int j = 0; j < 2; ++j) gload16(gB[j] + k0, lB[j] + cb * 8192);
  };

  int offA[4], offB[4];
#pragma unroll
  for (int mt = 0; mt < 4; ++mt) {
    const int rowA = wm * 64 + mt * 16 + lr;
    offA[mt] = rowA * 32 + ((lg ^ ((rowA >> 1) & 3)) << 3);
    const int rowB = wn * 64 + mt * 16 + lr;
    offB[mt] = 4096 + rowB * 32 + ((lg ^ ((rowB >> 1) & 3)) << 3);
  }

  f32x4 acc[4][4];
#pragma unroll
  for (int i = 0; i < 4; ++i)
#pragma unroll
    for (int j = 0; j < 4; ++j) acc[i][j] = (f32x4){0.f, 0.f, 0.f, 0.f};

  const int NT = kLen >> 5;
  stage(0, 0);
  stage(32, 1);

  for (int tt = 0; tt < NT; ++tt) {
    const int cb = tt & 1;
    if (tt + 1 < NT) asm volatile("s_waitcnt vmcnt(4)" ::: "memory");
    else             asm volatile("s_waitcnt vmcnt(0)" ::: "memory");
    __builtin_amdgcn_s_barrier();
    const unsigned short* buf = L + cb * 8192;
    bf16x8 af[4], bfr[4];
#pragma unroll
    for (int mt = 0; mt < 4; ++mt) {
      af[mt]  = ld_frag(buf + offA[mt]);
      bfr[mt] = ld_frag(buf + offB[mt]);
    }
    __builtin_amdgcn_s_setprio(1);
#pragma unroll
    for (int mt = 0; mt < 4; ++mt)
#pragma unroll
      for (int nt = 0; nt < 4; ++nt)
        acc[mt][nt] = __builtin_amdgcn_mfma_f32_16x16x32_bf16(af[mt], bfr[nt], acc[mt][nt], 0, 0, 0);
    __builtin_amdgcn_s_setprio(0);
    __builtin_amdgcn_s_barrier();
    if (tt + 2 < NT) stage((tt + 2) << 5, cb);
  }

  const int rbase = bm * 128 + wm * 64;
  const int cbase = bn * 128 + wn * 64;
  float* outP = outF;
  if constexpr (EPI == 4) outP = outF + (size_t)blockIdx.y * SEQ * N;

  if constexpr (EPI == 5) {
    unsigned short* vT = (unsigned short*)outF;    // [DM][SEQ]
    const bool isV = (bn * 128 >= 2048);           // 2048 boundary is 128-aligned
    if (isV) {
#pragma unroll
      for (int mt = 0; mt < 4; ++mt) {
#pragma unroll
        for (int nt = 0; nt < 4; ++nt) {
          const int d = cbase + nt * 16 + lr - 2048;
          const int row0 = rbase + mt * 16 + lg * 4;
          ushort4 o4;
          o4.x = f2bf(acc[mt][nt][0]);
          o4.y = f2bf(acc[mt][nt][1]);
          o4.z = f2bf(acc[mt][nt][2]);
          o4.w = f2bf(acc[mt][nt][3]);
          *(ushort4*)&vT[(size_t)d * SEQ + row0] = o4;
        }
      }
    } else {
#pragma unroll
      for (int mt = 0; mt < 4; ++mt)
#pragma unroll
        for (int nt = 0; nt < 4; ++nt) {
          const int col = cbase + nt * 16 + lr;
#pragma unroll
          for (int r = 0; r < 4; ++r) {
            const int row = rbase + mt * 16 + lg * 4 + r;
            outB[(size_t)row * N + col] = f2bf(acc[mt][nt][r]);
          }
        }
    }
    return;
  }

#pragma unroll
  for (int mt = 0; mt < 4; ++mt) {
#pragma unroll
    for (int nt = 0; nt < 4; ++nt) {
      const int col = cbase + nt * 16 + lr;
      float bv = 0.f;
      if constexpr (EPI == 1 || EPI == 2) bv = bias[col];
#pragma unroll
      for (int r = 0; r < 4; ++r) {
        const int row = rbase + mt * 16 + lg * 4 + r;
        float v = acc[mt][nt][r] + bv;
        if constexpr (EPI == 2) v = 0.5f * v * (1.f + erff(v * 0.70710678118f));
        if constexpr (EPI == 0 || EPI == 2) outB[(size_t)row * N + col] = f2bf(v);
        else                                outP[(size_t)row * N + col] = v;
      }
    }
  }
}

// ---- fused causal ReLA attention: balanced strip pairs + kv-split (z=2) ----
// ReLA has no softmax normalization -> O is LINEAR in kv-tiles: each z-half
// accumulates a partial O into its f32 slab; k_ored sums. K/V double-buffered
// with counted vmcnt(4) + raw s_barrier (no full drains in the loop).
__global__ __launch_bounds__(256)
void k_rela_attn(const unsigned short* __restrict__ qkv,
                 const unsigned short* __restrict__ vT,
                 float* __restrict__ osl) {
  const int jb = blockIdx.x;      // 0..15
  const int hd = blockIdx.y;      // 0..15
  const int z  = blockIdx.z;      // 0..1
  const int qbA = jb, qbB = 31 - jb;
  const int ha = (qbA + 2) >> 1, hb = (qbB + 2) >> 1;
  const int t = threadIdx.x, lane = t & 63, w = t >> 6;
  const int lr = lane & 15, lg = lane >> 4;

  __shared__ __align__(16) unsigned short Qs[128 * 64];
  __shared__ __align__(16) unsigned short Ks[2][64 * 64];
  __shared__ __align__(16) unsigned short Vs[2][64 * 64];
  __shared__ __align__(16) unsigned short Ps[4][16 * 72];

  const int sr8 = lane >> 3;
  const int sch = ((lane & 7) ^ sr8) << 3;

#pragma unroll
  for (int qi = 0; qi < 4; ++qi) {
    const int i = w * 4 + qi;
    const int rl = i * 8 + sr8;
    const int grow = (rl < 64) ? (qbA * 64 + rl) : (qbB * 64 + rl - 64);
    gload16(qkv + (size_t)grow * (3 * DM) + hd * DHD + sch, Qs + i * 512);
  }
  __syncthreads();

  bf16x8 qfA[2], qfB[2];
#pragma unroll
  for (int ks = 0; ks < 2; ++ks) {
    const int rowA = w * 16 + lr;
    qfA[ks] = ld_frag(&Qs[rowA * 64 + (((ks * 4 + lg) ^ (lr & 7)) << 3)]);
    const int rowB = 64 + w * 16 + lr;
    qfB[ks] = ld_frag(&Qs[rowB * 64 + (((ks * 4 + lg) ^ (lr & 7)) << 3)]);
  }

  const f32x4 zero = {0.f, 0.f, 0.f, 0.f};
  f32x4 accA[4], accB[4];
#pragma unroll
  for (int nt = 0; nt < 4; ++nt) { accA[nt] = zero; accB[nt] = zero; }

  auto stage = [&](int kt, int cb) {
#pragma unroll
    for (int qi = 0; qi < 2; ++qi) {
      const int i = w * 2 + qi;
      const int rl = i * 8 + sr8;
      gload16(qkv + (size_t)(kt * 64 + rl) * (3 * DM) + DM + hd * DHD + sch, &Ks[cb][i * 512]);
      gload16(vT + (size_t)(hd * DHD + rl) * SEQ + kt * 64 + sch, &Vs[cb][i * 512]);
    }
  };

  auto tile_step = [&](const bf16x8* qf, f32x4* acc, int qb, int kt, int cb) {
    f32x4 sv[4];
#pragma unroll
    for (int nt = 0; nt < 4; ++nt) sv[nt] = zero;
#pragma unroll
    for (int ks = 0; ks < 2; ++ks)
#pragma unroll
      for (int nt = 0; nt < 4; ++nt) {
        bf16x8 kf = ld_frag(&Ks[cb][(nt * 16 + lr) * 64 + (((ks * 4 + lg) ^ (lr & 7)) << 3)]);
        sv[nt] = __builtin_amdgcn_mfma_f32_16x16x32_bf16(qf[ks], kf, sv[nt], 0, 0, 0);
      }
    const bool diag = (kt == qb);
#pragma unroll
    for (int nt = 0; nt < 4; ++nt)
#pragma unroll
      for (int r = 0; r < 4; ++r) {
        float v = fmaxf(sv[nt][r], 0.f) * 0.125f;
        if (diag) {
          const int ii = w * 16 + lg * 4 + r;
          const int jj = nt * 16 + lr;
          if (jj > ii) v = 0.f;
        }
        Ps[w][(lg * 4 + r) * 72 + nt * 16 + lr] = f2bf(v);
      }
#pragma unroll
    for (int ks = 0; ks < 2; ++ks) {
      bf16x8 pf = ld_frag(&Ps[w][lr * 72 + ks * 32 + lg * 8]);
#pragma unroll
      for (int nt = 0; nt < 4; ++nt) {
        bf16x8 vf = ld_frag(&Vs[cb][(nt * 16 + lr) * 64 + (((ks * 4 + lg) ^ (lr & 7)) << 3)]);
        acc[nt] = __builtin_amdgcn_mfma_f32_16x16x32_bf16(pf, vf, acc[nt], 0, 0, 0);
      }
    }
  };

  auto run = [&](int beg, int end, int mode) {
    if (beg >= end) return;
    stage(beg, 0);
    for (int kt = beg; kt < end; ++kt) {
      const int cb = (kt - beg) & 1;
      if (kt + 1 < end) {
        stage(kt + 1, cb ^ 1);
        asm volatile("s_waitcnt vmcnt(4)" ::: "memory");
      } else {
        asm volatile("s_waitcnt vmcnt(0)" ::: "memory");
      }
      __builtin_amdgcn_s_barrier();
      if (mode != 1) tile_step(qfB, accB, qbB, kt, cb);
      if (mode == 1 || (mode == 0 && kt < ha)) tile_step(qfA, accA, qbA, kt, cb);
      __builtin_amdgcn_s_barrier();
    }
  };

  if (z == 0) {
    run(0, hb, 0);
  } else {
    run(ha, qbA + 1, 1);
    run(hb, qbB + 1, 2);
  }

  float* op = osl + (size_t)z * SEQ * DM;
#pragma unroll
  for (int nt = 0; nt < 4; ++nt)
#pragma unroll
    for (int r = 0; r < 4; ++r) {
      const int col = hd * DHD + nt * 16 + lr;
      const int rowA = qbA * 64 + w * 16 + lg * 4 + r;
      op[(size_t)rowA * DM + col] = accA[nt][r];
      const int rowB = qbB * 64 + w * 16 + lg * 4 + r;
      op[(size_t)rowB * DM + col] = accB[nt][r];
    }
}

extern "C" void kernel_launch(void* const* d_in, const int* in_sizes, int n_in,
                              void* d_out, int out_size, void* d_ws, size_t ws_size,
                              hipStream_t stream) {
  const int*   x       = (const int*)d_in[0];
  const float* tok_emb = (const float*)d_in[1];
  const float* pos_emb = (const float*)d_in[2];
  const float* attn_ng = (const float*)d_in[3];
  const float* attn_nb = (const float*)d_in[4];
  const float* wqkv    = (const float*)d_in[5];
  const float* wo      = (const float*)d_in[6];
  const float* bo      = (const float*)d_in[7];
  const float* out_ng  = (const float*)d_in[8];
  const float* out_nb  = (const float*)d_in[9];
  const float* ff_ng   = (const float*)d_in[10];
  const float* ff_nb   = (const float*)d_in[11];
  const float* w1      = (const float*)d_in[12];
  const float* b1      = (const float*)d_in[13];
  const float* w2      = (const float*)d_in[14];
  const float* b2      = (const float*)d_in[15];
  const float* fin_g   = (const float*)d_in[16];
  const float* fin_b   = (const float*)d_in[17];
  const float* w_logit = (const float*)d_in[18];
  const float* b_logit = (const float*)d_in[19];
  float* out = (float*)d_out;

  char* ws = (char*)d_ws;
  size_t off = 0;
  auto alloc = [&](size_t bytes) -> void* {
    void* p = ws + off;
    off = (off + bytes + 255) & ~(size_t)255;
    return p;
  };
  unsigned short* wqkvT = (unsigned short*)alloc(4ull * 3072 * 1024 * 2);
  unsigned short* woT   = (unsigned short*)alloc(4ull * 1024 * 1024 * 2);
  unsigned short* w1T   = (unsigned short*)alloc(4ull * 4096 * 1024 * 2);
  unsigned short* w2T   = (unsigned short*)alloc(4ull * 1024 * 4096 * 2);
  unsigned short* wlogT = (unsigned short*)alloc((size_t)NV * 1024 * 2);
  float*          h     = (float*)alloc((size_t)SEQ * DM * 4);
  unsigned short* ybf   = (unsigned short*)alloc((size_t)SEQ * DM * 2);
  unsigned short* qkvbf = (unsigned short*)alloc((size_t)SEQ * 3 * DM * 2);
  unsigned short* vTb   = (unsigned short*)alloc((size_t)DM * SEQ * 2);
  unsigned short* obf   = (unsigned short*)alloc((size_t)SEQ * DM * 2);
  unsigned short* ffbf  = (unsigned short*)alloc((size_t)SEQ * FFD * 2);
  float*          slabs = (float*)alloc(4ull * SEQ * DM * 4);
  (void)ws_size; (void)in_sizes; (void)n_in; (void)out_size;

  const dim3 B(256);

  k_transpose_bf16<<<dim3(16, 48, 4), B, 0, stream>>>(wqkv, wqkvT, 1024, 3072, (size_t)1024 * 3072);
  k_transpose_bf16<<<dim3(16, 16, 4), B, 0, stream>>>(wo, woT, 1024, 1024, (size_t)1024 * 1024);
  k_transpose_bf16<<<dim3(16, 64, 4), B, 0, stream>>>(w1, w1T, 1024, 4096, (size_t)1024 * 4096);
  k_transpose_bf16<<<dim3(64, 16, 4), B, 0, stream>>>(w2, w2T, 4096, 1024, (size_t)4096 * 1024);
  k_transpose_bf16<<<dim3(16, 500, 1), B, 0, stream>>>(w_logit, wlogT, 1024, NV, 0);

  k_embed<<<SEQ, B, 0, stream>>>(x, tok_emb, pos_emb, h);
  k_ln_bf16<<<SEQ, B, 0, stream>>>(h, attn_ng, attn_nb, ybf);

  for (int l = 0; l < 4; ++l) {
    // qkv GEMM: Q,K -> qkvbf; V -> vTb (transposed) in the epilogue
    k_gemm4<5><<<dim3(384), B, 0, stream>>>(
        ybf, wqkvT + (size_t)l * 3072 * 1024, (float*)vTb, qkvbf, nullptr, 3072, 1024, 1024, 16);
    k_rela_attn<<<dim3(16, NH, 2), B, 0, stream>>>(qkvbf, vTb, slabs);
    k_ored<<<SEQ, B, 0, stream>>>(slabs, obf);
    k_gemm4<4><<<dim3(128, 4), B, 0, stream>>>(
        obf, woT + (size_t)l * 1024 * 1024, slabs, nullptr, nullptr, 1024, 1024, 256, 16);
    k_addslab_ln_ln<<<SEQ, B, 0, stream>>>(h, slabs, bo + l * DM,
                                           out_ng + l * DM, out_nb + l * DM,
                                           ff_ng + l * DM, ff_nb + l * DM, ybf);
    k_gemm4<2><<<dim3(512), B, 0, stream>>>(
        ybf, w1T + (size_t)l * 4096 * 1024, nullptr, ffbf, b1 + l * FFD, 4096, 1024, 1024, 16);
    k_gemm4<4><<<dim3(128, 4), B, 0, stream>>>(
        ffbf, w2T + (size_t)l * 1024 * 4096, slabs, nullptr, nullptr, 1024, 4096, 1024, 16);
    const float* ng = (l < 3) ? (attn_ng + (l + 1) * DM) : fin_g;
    const float* nb = (l < 3) ? (attn_nb + (l + 1) * DM) : fin_b;
    k_redadd_ln<<<SEQ, B, 0, stream>>>(h, slabs, b2 + l * DM, ng, nb, ybf);
  }

  k_gemm4<1><<<dim3(4000), B, 0, stream>>>(ybf, wlogT, out, nullptr, b_logit, NV, 1024, 1024, 16);
}

// Round 17
// 1017.242 us; speedup vs baseline: 1.0396x; 1.0031x over previous
//
#include <hip/hip_runtime.h>
#include <hip/hip_bf16.h>
#include <math.h>

#define SEQ   2048
#define DM    1024
#define NH    16
#define DHD   64
#define FFD   4096
#define NV    32000

typedef __bf16 bf16x8 __attribute__((ext_vector_type(8)));
typedef float  f32x4  __attribute__((ext_vector_type(4)));

typedef __attribute__((address_space(1))) void* gas_ptr;
typedef __attribute__((address_space(3))) void* las_ptr;

static __device__ __forceinline__ void gload16(const void* g, void* l) {
  __builtin_amdgcn_global_load_lds((gas_ptr)g, (las_ptr)l, 16, 0, 0);
}

static __device__ __forceinline__ unsigned short f2bf(float f) {
  unsigned int x = __float_as_uint(f);
  return (unsigned short)((x + 0x7fffu + ((x >> 16) & 1u)) >> 16);
}

static __device__ __forceinline__ bf16x8 ld_frag(const unsigned short* p) {
  union { uint4 u; bf16x8 v; } r;
  r.u = *(const uint4*)p;
  return r.v;
}

// ---- transpose + f32->bf16 convert, batched over blockIdx.z layers ----
__global__ __launch_bounds__(256)
void k_transpose_bf16(const float* __restrict__ in, unsigned short* __restrict__ out,
                      int K, int N, size_t lstride) {
  in  += (size_t)blockIdx.z * lstride;
  out += (size_t)blockIdx.z * lstride;
  __shared__ float tl[64 * 65];
  const int bk = blockIdx.x * 64, bn = blockIdx.y * 64;
  const int t = threadIdx.x;
  const int tx = t & 15, ty = t >> 4;
#pragma unroll
  for (int i = 0; i < 4; ++i) {
    const int r = i * 16 + ty;
    float4 v = *(const float4*)&in[(size_t)(bk + r) * N + bn + tx * 4];
    tl[(tx * 4 + 0) * 65 + r] = v.x;
    tl[(tx * 4 + 1) * 65 + r] = v.y;
    tl[(tx * 4 + 2) * 65 + r] = v.z;
    tl[(tx * 4 + 3) * 65 + r] = v.w;
  }
  __syncthreads();
#pragma unroll
  for (int j = 0; j < 2; ++j) {
    const int f = j * 256 + t;
    const int n = f >> 3, kc = (f & 7) * 8;
    union { unsigned short u[8]; uint4 v; } pk;
#pragma unroll
    for (int e = 0; e < 8; ++e) pk.u[e] = f2bf(tl[n * 65 + kc + e]);
    *(uint4*)&out[(size_t)(bn + n) * K + bk + kc] = pk.v;
  }
}

// ---- fused embedding + LayerNorm: h = tok[x]+pos; ybf = bf16(LN(h)) ----
__global__ __launch_bounds__(256)
void k_embed_ln(const int* __restrict__ x, const float* __restrict__ tok,
                const float* __restrict__ pos, float* __restrict__ h,
                const float* __restrict__ g, const float* __restrict__ b,
                unsigned short* __restrict__ out) {
  const int row = blockIdx.x, t = threadIdx.x;
  __shared__ float ls[4], lq[4];
  const int d = t * 4;
  const int tk = x[row];
  float4 a = *(const float4*)(tok + (size_t)tk * DM + d);
  float4 p = *(const float4*)(pos + (size_t)row * DM + d);
  float4 hv;
  hv.x = a.x + p.x; hv.y = a.y + p.y; hv.z = a.z + p.z; hv.w = a.w + p.w;
  *(float4*)(h + (size_t)row * DM + d) = hv;
  float s = hv.x + hv.y + hv.z + hv.w;
  float q = hv.x * hv.x + hv.y * hv.y + hv.z * hv.z + hv.w * hv.w;
#pragma unroll
  for (int o = 32; o; o >>= 1) { s += __shfl_xor(s, o); q += __shfl_xor(q, o); }
  if ((t & 63) == 0) { ls[t >> 6] = s; lq[t >> 6] = q; }
  __syncthreads();
  s = ls[0] + ls[1] + ls[2] + ls[3];
  q = lq[0] + lq[1] + lq[2] + lq[3];
  const float mean = s * (1.f / DM);
  const float rstd = rsqrtf(q * (1.f / DM) - mean * mean + 1e-5f);
  float4 gg = *(const float4*)(g + d);
  float4 bb = *(const float4*)(b + d);
  ushort4 o4;
  o4.x = f2bf((hv.x - mean) * rstd * gg.x + bb.x);
  o4.y = f2bf((hv.y - mean) * rstd * gg.y + bb.y);
  o4.z = f2bf((hv.z - mean) * rstd * gg.z + bb.z);
  o4.w = f2bf((hv.w - mean) * rstd * gg.w + bb.w);
  *(ushort4*)(out + (size_t)row * DM + d) = o4;
}

// ---- obf = bf16(slab0 + slab1) ----
__global__ __launch_bounds__(256)
void k_ored(const float* __restrict__ sl, unsigned short* __restrict__ obf) {
  const int row = blockIdx.x, t = threadIdx.x;
  const size_t idx = (size_t)row * DM + t * 4;
  float4 a = *(const float4*)(sl + idx);
  float4 b = *(const float4*)(sl + (size_t)SEQ * DM + idx);
  ushort4 o4;
  o4.x = f2bf(a.x + b.x);
  o4.y = f2bf(a.y + b.y);
  o4.z = f2bf(a.z + b.z);
  o4.w = f2bf(a.w + b.w);
  *(ushort4*)(obf + idx) = o4;
}

// ---- h += LN1(bo + sum4 slabs); out = bf16(LN2(h)) ----
__global__ __launch_bounds__(256)
void k_addslab_ln_ln(float* __restrict__ h, const float* __restrict__ sl,
                     const float* __restrict__ bo,
                     const float* __restrict__ g1, const float* __restrict__ b1,
                     const float* __restrict__ g2, const float* __restrict__ b2,
                     unsigned short* __restrict__ out) {
  const int row = blockIdx.x, t = threadIdx.x;
  __shared__ float ls[4], lq[4], ls2[4], lq2[4];
  const size_t idx = (size_t)row * DM + t * 4;
  float4 v = *(const float4*)(bo + t * 4);
#pragma unroll
  for (int c = 0; c < 4; ++c) {
    float4 p = *(const float4*)(sl + (size_t)c * SEQ * DM + idx);
    v.x += p.x; v.y += p.y; v.z += p.z; v.w += p.w;
  }
  float s = v.x + v.y + v.z + v.w;
  float q = v.x * v.x + v.y * v.y + v.z * v.z + v.w * v.w;
#pragma unroll
  for (int o = 32; o; o >>= 1) { s += __shfl_xor(s, o); q += __shfl_xor(q, o); }
  if ((t & 63) == 0) { ls[t >> 6] = s; lq[t >> 6] = q; }
  __syncthreads();
  s = ls[0] + ls[1] + ls[2] + ls[3];
  q = lq[0] + lq[1] + lq[2] + lq[3];
  const float mean = s * (1.f / DM);
  const float rstd = rsqrtf(q * (1.f / DM) - mean * mean + 1e-5f);
  float4 gg = *(const float4*)(g1 + t * 4);
  float4 bb = *(const float4*)(b1 + t * 4);
  float4 hv = *(const float4*)(h + idx);
  hv.x += (v.x - mean) * rstd * gg.x + bb.x;
  hv.y += (v.y - mean) * rstd * gg.y + bb.y;
  hv.z += (v.z - mean) * rstd * gg.z + bb.z;
  hv.w += (v.w - mean) * rstd * gg.w + bb.w;
  *(float4*)(h + idx) = hv;
  float s2 = hv.x + hv.y + hv.z + hv.w;
  float q2 = hv.x * hv.x + hv.y * hv.y + hv.z * hv.z + hv.w * hv.w;
#pragma unroll
  for (int o = 32; o; o >>= 1) { s2 += __shfl_xor(s2, o); q2 += __shfl_xor(q2, o); }
  if ((t & 63) == 0) { ls2[t >> 6] = s2; lq2[t >> 6] = q2; }
  __syncthreads();
  s2 = ls2[0] + ls2[1] + ls2[2] + ls2[3];
  q2 = lq2[0] + lq2[1] + lq2[2] + lq2[3];
  const float mean2 = s2 * (1.f / DM);
  const float rstd2 = rsqrtf(q2 * (1.f / DM) - mean2 * mean2 + 1e-5f);
  float4 g2v = *(const float4*)(g2 + t * 4);
  float4 b2v = *(const float4*)(b2 + t * 4);
  ushort4 o4;
  o4.x = f2bf((hv.x - mean2) * rstd2 * g2v.x + b2v.x);
  o4.y = f2bf((hv.y - mean2) * rstd2 * g2v.y + b2v.y);
  o4.z = f2bf((hv.z - mean2) * rstd2 * g2v.z + b2v.z);
  o4.w = f2bf((hv.w - mean2) * rstd2 * g2v.w + b2v.w);
  *(ushort4*)(out + (size_t)row * DM + t * 4) = o4;
}

// ---- h += b2 + sum4 slabs; ybf = bf16(LN(h, g, b)) ----
__global__ __launch_bounds__(256)
void k_redadd_ln(float* __restrict__ h, const float* __restrict__ sl,
                 const float* __restrict__ b2,
                 const float* __restrict__ g, const float* __restrict__ b,
                 unsigned short* __restrict__ out) {
  const int row = blockIdx.x, t = threadIdx.x;
  __shared__ float ls[4], lq[4];
  const size_t idx = (size_t)row * DM + t * 4;
  float4 hv = *(const float4*)(h + idx);
  float4 bb = *(const float4*)(b2 + t * 4);
  hv.x += bb.x; hv.y += bb.y; hv.z += bb.z; hv.w += bb.w;
#pragma unroll
  for (int c = 0; c < 4; ++c) {
    float4 p = *(const float4*)(sl + (size_t)c * SEQ * DM + idx);
    hv.x += p.x; hv.y += p.y; hv.z += p.z; hv.w += p.w;
  }
  *(float4*)(h + idx) = hv;
  float s = hv.x + hv.y + hv.z + hv.w;
  float q = hv.x * hv.x + hv.y * hv.y + hv.z * hv.z + hv.w * hv.w;
#pragma unroll
  for (int o = 32; o; o >>= 1) { s += __shfl_xor(s, o); q += __shfl_xor(q, o); }
  if ((t & 63) == 0) { ls[t >> 6] = s; lq[t >> 6] = q; }
  __syncthreads();
  s = ls[0] + ls[1] + ls[2] + ls[3];
  q = lq[0] + lq[1] + lq[2] + lq[3];
  const float mean = s * (1.f / DM);
  const float rstd = rsqrtf(q * (1.f / DM) - mean * mean + 1e-5f);
  float4 gg = *(const float4*)(g + t * 4);
  float4 b1 = *(const float4*)(b + t * 4);
  ushort4 o4;
  o4.x = f2bf((hv.x - mean) * rstd * gg.x + b1.x);
  o4.y = f2bf((hv.y - mean) * rstd * gg.y + b1.y);
  o4.z = f2bf((hv.z - mean) * rstd * gg.z + b1.z);
  o4.w = f2bf((hv.w - mean) * rstd * gg.w + b1.w);
  *(ushort4*)(out + (size_t)row * DM + t * 4) = o4;
}

// ---- GEMM v4: 128x128, 4 waves, BK=32 dbuf (32KB LDS), 3 blocks/CU ----
// EPI: 0 bf16; 1 +bias f32; 2 +bias gelu bf16; 4 slab f32 (blockIdx.y);
//      5 qkv: cols<2048 -> bf16 outB; cols>=2048 (V) -> transposed vT[d][s]
template<int EPI>
__global__ __launch_bounds__(256)
void k_gemm4(const unsigned short* __restrict__ A, const unsigned short* __restrict__ Bt,
             float* __restrict__ outF, unsigned short* __restrict__ outB,
             const float* __restrict__ bias, int N, int K, int kLen, int gm) {
  __shared__ __align__(16) unsigned short L[16384];
  const int nwg = gridDim.x, pid = blockIdx.x;
  const int qq = nwg >> 3, rr = nwg & 7;
  const int xcd = pid & 7, lo = pid >> 3;
  const int wg = ((xcd < rr) ? xcd * (qq + 1) : rr * (qq + 1) + (xcd - rr) * qq) + lo;
  const int bm = wg % gm, bn = wg / gm;
  const int kOff = blockIdx.y * kLen;
  const int t = threadIdx.x, lane = t & 63, w = t >> 6;
  const int wm = w >> 1, wn = w & 1, lr = lane & 15, lg = lane >> 4;

  const unsigned short* gA[2]; const unsigned short* gB[2];
  unsigned short* lA[2]; unsigned short* lB[2];
#pragma unroll
  for (int j = 0; j < 2; ++j) {
    const int f = j * 256 + t;
    const int row = f >> 2;
    const int c = (f & 3) ^ ((row >> 1) & 3);
    gA[j] = A  + (size_t)(bm * 128 + row) * K + kOff + c * 8;
    gB[j] = Bt + (size_t)(bn * 128 + row) * K + kOff + c * 8;
    lA[j] = L + f * 8;
    lB[j] = L + 4096 + f * 8;
  }
  auto stage = [&](int k0, int cb) {
#pragma unroll
    for (int j = 0; j < 2; ++j) gload16(gA[j] + k0, lA[j] + cb * 8192);
#pragma unroll
    for (int j = 0; j < 2; ++j) gload16(gB[j] + k0, lB[j] + cb * 8192);
  };

  int offA[4], offB[4];
#pragma unroll
  for (int mt = 0; mt < 4; ++mt) {
    const int rowA = wm * 64 + mt * 16 + lr;
    offA[mt] = rowA * 32 + ((lg ^ ((rowA >> 1) & 3)) << 3);
    const int rowB = wn * 64 + mt * 16 + lr;
    offB[mt] = 4096 + rowB * 32 + ((lg ^ ((rowB >> 1) & 3)) << 3);
  }

  f32x4 acc[4][4];
#pragma unroll
  for (int i = 0; i < 4; ++i)
#pragma unroll
    for (int j = 0; j < 4; ++j) acc[i][j] = (f32x4){0.f, 0.f, 0.f, 0.f};

  const int NT = kLen >> 5;
  stage(0, 0);
  stage(32, 1);

  for (int tt = 0; tt < NT; ++tt) {
    const int cb = tt & 1;
    if (tt + 1 < NT) asm volatile("s_waitcnt vmcnt(4)" ::: "memory");
    else             asm volatile("s_waitcnt vmcnt(0)" ::: "memory");
    __builtin_amdgcn_s_barrier();
    const unsigned short* buf = L + cb * 8192;
    bf16x8 af[4], bfr[4];
#pragma unroll
    for (int mt = 0; mt < 4; ++mt) {
      af[mt]  = ld_frag(buf + offA[mt]);
      bfr[mt] = ld_frag(buf + offB[mt]);
    }
    __builtin_amdgcn_s_setprio(1);
#pragma unroll
    for (int mt = 0; mt < 4; ++mt)
#pragma unroll
      for (int nt = 0; nt < 4; ++nt)
        acc[mt][nt] = __builtin_amdgcn_mfma_f32_16x16x32_bf16(af[mt], bfr[nt], acc[mt][nt], 0, 0, 0);
    __builtin_amdgcn_s_setprio(0);
    __builtin_amdgcn_s_barrier();
    if (tt + 2 < NT) stage((tt + 2) << 5, cb);
  }

  const int rbase = bm * 128 + wm * 64;
  const int cbase = bn * 128 + wn * 64;
  float* outP = outF;
  if constexpr (EPI == 4) outP = outF + (size_t)blockIdx.y * SEQ * N;

  if constexpr (EPI == 5) {
    unsigned short* vT = (unsigned short*)outF;    // [DM][SEQ]
    const bool isV = (bn * 128 >= 2048);           // 2048 boundary is 128-aligned
    if (isV) {
#pragma unroll
      for (int mt = 0; mt < 4; ++mt) {
#pragma unroll
        for (int nt = 0; nt < 4; ++nt) {
          const int d = cbase + nt * 16 + lr - 2048;
          const int row0 = rbase + mt * 16 + lg * 4;
          ushort4 o4;
          o4.x = f2bf(acc[mt][nt][0]);
          o4.y = f2bf(acc[mt][nt][1]);
          o4.z = f2bf(acc[mt][nt][2]);
          o4.w = f2bf(acc[mt][nt][3]);
          *(ushort4*)&vT[(size_t)d * SEQ + row0] = o4;
        }
      }
    } else {
#pragma unroll
      for (int mt = 0; mt < 4; ++mt)
#pragma unroll
        for (int nt = 0; nt < 4; ++nt) {
          const int col = cbase + nt * 16 + lr;
#pragma unroll
          for (int r = 0; r < 4; ++r) {
            const int row = rbase + mt * 16 + lg * 4 + r;
            outB[(size_t)row * N + col] = f2bf(acc[mt][nt][r]);
          }
        }
    }
    return;
  }

#pragma unroll
  for (int mt = 0; mt < 4; ++mt) {
#pragma unroll
    for (int nt = 0; nt < 4; ++nt) {
      const int col = cbase + nt * 16 + lr;
      float bv = 0.f;
      if constexpr (EPI == 1 || EPI == 2) bv = bias[col];
#pragma unroll
      for (int r = 0; r < 4; ++r) {
        const int row = rbase + mt * 16 + lg * 4 + r;
        float v = acc[mt][nt][r] + bv;
        if constexpr (EPI == 2) v = 0.5f * v * (1.f + erff(v * 0.70710678118f));
        if constexpr (EPI == 0 || EPI == 2) outB[(size_t)row * N + col] = f2bf(v);
        else                                outP[(size_t)row * N + col] = v;
      }
    }
  }
}

// ---- fused causal ReLA attention: balanced strip pairs + kv-split (z=2) ----
__global__ __launch_bounds__(256)
void k_rela_attn(const unsigned short* __restrict__ qkv,
                 const unsigned short* __restrict__ vT,
                 float* __restrict__ osl) {
  const int jb = blockIdx.x;      // 0..15
  const int hd = blockIdx.y;      // 0..15
  const int z  = blockIdx.z;      // 0..1
  const int qbA = jb, qbB = 31 - jb;
  const int ha = (qbA + 2) >> 1, hb = (qbB + 2) >> 1;
  const int t = threadIdx.x, lane = t & 63, w = t >> 6;
  const int lr = lane & 15, lg = lane >> 4;

  __shared__ __align__(16) unsigned short Qs[128 * 64];
  __shared__ __align__(16) unsigned short Ks[2][64 * 64];
  __shared__ __align__(16) unsigned short Vs[2][64 * 64];
  __shared__ __align__(16) unsigned short Ps[4][16 * 72];

  const int sr8 = lane >> 3;
  const int sch = ((lane & 7) ^ sr8) << 3;

#pragma unroll
  for (int qi = 0; qi < 4; ++qi) {
    const int i = w * 4 + qi;
    const int rl = i * 8 + sr8;
    const int grow = (rl < 64) ? (qbA * 64 + rl) : (qbB * 64 + rl - 64);
    gload16(qkv + (size_t)grow * (3 * DM) + hd * DHD + sch, Qs + i * 512);
  }
  __syncthreads();

  bf16x8 qfA[2], qfB[2];
#pragma unroll
  for (int ks = 0; ks < 2; ++ks) {
    const int rowA = w * 16 + lr;
    qfA[ks] = ld_frag(&Qs[rowA * 64 + (((ks * 4 + lg) ^ (lr & 7)) << 3)]);
    const int rowB = 64 + w * 16 + lr;
    qfB[ks] = ld_frag(&Qs[rowB * 64 + (((ks * 4 + lg) ^ (lr & 7)) << 3)]);
  }

  const f32x4 zero = {0.f, 0.f, 0.f, 0.f};
  f32x4 accA[4], accB[4];
#pragma unroll
  for (int nt = 0; nt < 4; ++nt) { accA[nt] = zero; accB[nt] = zero; }

  auto stage = [&](int kt, int cb) {
#pragma unroll
    for (int qi = 0; qi < 2; ++qi) {
      const int i = w * 2 + qi;
      const int rl = i * 8 + sr8;
      gload16(qkv + (size_t)(kt * 64 + rl) * (3 * DM) + DM + hd * DHD + sch, &Ks[cb][i * 512]);
      gload16(vT + (size_t)(hd * DHD + rl) * SEQ + kt * 64 + sch, &Vs[cb][i * 512]);
    }
  };

  auto tile_step = [&](const bf16x8* qf, f32x4* acc, int qb, int kt, int cb) {
    f32x4 sv[4];
#pragma unroll
    for (int nt = 0; nt < 4; ++nt) sv[nt] = zero;
#pragma unroll
    for (int ks = 0; ks < 2; ++ks)
#pragma unroll
      for (int nt = 0; nt < 4; ++nt) {
        bf16x8 kf = ld_frag(&Ks[cb][(nt * 16 + lr) * 64 + (((ks * 4 + lg) ^ (lr & 7)) << 3)]);
        sv[nt] = __builtin_amdgcn_mfma_f32_16x16x32_bf16(qf[ks], kf, sv[nt], 0, 0, 0);
      }
    const bool diag = (kt == qb);
#pragma unroll
    for (int nt = 0; nt < 4; ++nt)
#pragma unroll
      for (int r = 0; r < 4; ++r) {
        float v = fmaxf(sv[nt][r], 0.f) * 0.125f;
        if (diag) {
          const int ii = w * 16 + lg * 4 + r;
          const int jj = nt * 16 + lr;
          if (jj > ii) v = 0.f;
        }
        Ps[w][(lg * 4 + r) * 72 + nt * 16 + lr] = f2bf(v);
      }
#pragma unroll
    for (int ks = 0; ks < 2; ++ks) {
      bf16x8 pf = ld_frag(&Ps[w][lr * 72 + ks * 32 + lg * 8]);
#pragma unroll
      for (int nt = 0; nt < 4; ++nt) {
        bf16x8 vf = ld_frag(&Vs[cb][(nt * 16 + lr) * 64 + (((ks * 4 + lg) ^ (lr & 7)) << 3)]);
        acc[nt] = __builtin_amdgcn_mfma_f32_16x16x32_bf16(pf, vf, acc[nt], 0, 0, 0);
      }
    }
  };

  auto run = [&](int beg, int end, int mode) {
    if (beg >= end) return;
    stage(beg, 0);
    for (int kt = beg; kt < end; ++kt) {
      const int cb = (kt - beg) & 1;
      if (kt + 1 < end) {
        stage(kt + 1, cb ^ 1);
        asm volatile("s_waitcnt vmcnt(4)" ::: "memory");
      } else {
        asm volatile("s_waitcnt vmcnt(0)" ::: "memory");
      }
      __builtin_amdgcn_s_barrier();
      if (mode != 1) tile_step(qfB, accB, qbB, kt, cb);
      if (mode == 1 || (mode == 0 && kt < ha)) tile_step(qfA, accA, qbA, kt, cb);
      __builtin_amdgcn_s_barrier();
    }
  };

  if (z == 0) {
    run(0, hb, 0);
  } else {
    run(ha, qbA + 1, 1);
    run(hb, qbB + 1, 2);
  }

  float* op = osl + (size_t)z * SEQ * DM;
#pragma unroll
  for (int nt = 0; nt < 4; ++nt)
#pragma unroll
    for (int r = 0; r < 4; ++r) {
      const int col = hd * DHD + nt * 16 + lr;
      const int rowA = qbA * 64 + w * 16 + lg * 4 + r;
      op[(size_t)rowA * DM + col] = accA[nt][r];
      const int rowB = qbB * 64 + w * 16 + lg * 4 + r;
      op[(size_t)rowB * DM + col] = accB[nt][r];
    }
}

extern "C" void kernel_launch(void* const* d_in, const int* in_sizes, int n_in,
                              void* d_out, int out_size, void* d_ws, size_t ws_size,
                              hipStream_t stream) {
  const int*   x       = (const int*)d_in[0];
  const float* tok_emb = (const float*)d_in[1];
  const float* pos_emb = (const float*)d_in[2];
  const float* attn_ng = (const float*)d_in[3];
  const float* attn_nb = (const float*)d_in[4];
  const float* wqkv    = (const float*)d_in[5];
  const float* wo      = (const float*)d_in[6];
  const float* bo      = (const float*)d_in[7];
  const float* out_ng  = (const float*)d_in[8];
  const float* out_nb  = (const float*)d_in[9];
  const float* ff_ng   = (const float*)d_in[10];
  const float* ff_nb   = (const float*)d_in[11];
  const float* w1      = (const float*)d_in[12];
  const float* b1      = (const float*)d_in[13];
  const float* w2      = (const float*)d_in[14];
  const float* b2      = (const float*)d_in[15];
  const float* fin_g   = (const float*)d_in[16];
  const float* fin_b   = (const float*)d_in[17];
  const float* w_logit = (const float*)d_in[18];
  const float* b_logit = (const float*)d_in[19];
  float* out = (float*)d_out;

  char* ws = (char*)d_ws;
  size_t off = 0;
  auto alloc = [&](size_t bytes) -> void* {
    void* p = ws + off;
    off = (off + bytes + 255) & ~(size_t)255;
    return p;
  };
  unsigned short* wqkvT = (unsigned short*)alloc(4ull * 3072 * 1024 * 2);
  unsigned short* woT   = (unsigned short*)alloc(4ull * 1024 * 1024 * 2);
  unsigned short* w1T   = (unsigned short*)alloc(4ull * 4096 * 1024 * 2);
  unsigned short* w2T   = (unsigned short*)alloc(4ull * 1024 * 4096 * 2);
  unsigned short* wlogT = (unsigned short*)alloc((size_t)NV * 1024 * 2);
  float*          h     = (float*)alloc((size_t)SEQ * DM * 4);
  unsigned short* ybf   = (unsigned short*)alloc((size_t)SEQ * DM * 2);
  unsigned short* qkvbf = (unsigned short*)alloc((size_t)SEQ * 3 * DM * 2);
  unsigned short* vTb   = (unsigned short*)alloc((size_t)DM * SEQ * 2);
  unsigned short* obf   = (unsigned short*)alloc((size_t)SEQ * DM * 2);
  unsigned short* ffbf  = (unsigned short*)alloc((size_t)SEQ * FFD * 2);
  float*          slabs = (float*)alloc(4ull * SEQ * DM * 4);
  (void)ws_size; (void)in_sizes; (void)n_in; (void)out_size;

  const dim3 B(256);

  k_transpose_bf16<<<dim3(16, 48, 4), B, 0, stream>>>(wqkv, wqkvT, 1024, 3072, (size_t)1024 * 3072);
  k_transpose_bf16<<<dim3(16, 16, 4), B, 0, stream>>>(wo, woT, 1024, 1024, (size_t)1024 * 1024);
  k_transpose_bf16<<<dim3(16, 64, 4), B, 0, stream>>>(w1, w1T, 1024, 4096, (size_t)1024 * 4096);
  k_transpose_bf16<<<dim3(64, 16, 4), B, 0, stream>>>(w2, w2T, 4096, 1024, (size_t)4096 * 1024);
  k_transpose_bf16<<<dim3(16, 500, 1), B, 0, stream>>>(w_logit, wlogT, 1024, NV, 0);

  k_embed_ln<<<SEQ, B, 0, stream>>>(x, tok_emb, pos_emb, h, attn_ng, attn_nb, ybf);

  for (int l = 0; l < 4; ++l) {
    // qkv GEMM: Q,K -> qkvbf; V -> vTb (transposed) in the epilogue
    k_gemm4<5><<<dim3(384), B, 0, stream>>>(
        ybf, wqkvT + (size_t)l * 3072 * 1024, (float*)vTb, qkvbf, nullptr, 3072, 1024, 1024, 16);
    k_rela_attn<<<dim3(16, NH, 2), B, 0, stream>>>(qkvbf, vTb, slabs);
    k_ored<<<SEQ, B, 0, stream>>>(slabs, obf);
    k_gemm4<4><<<dim3(128, 4), B, 0, stream>>>(
        obf, woT + (size_t)l * 1024 * 1024, slabs, nullptr, nullptr, 1024, 1024, 256, 16);
    k_addslab_ln_ln<<<SEQ, B, 0, stream>>>(h, slabs, bo + l * DM,
                                           out_ng + l * DM, out_nb + l * DM,
                                           ff_ng + l * DM, ff_nb + l * DM, ybf);
    k_gemm4<2><<<dim3(512), B, 0, stream>>>(
        ybf, w1T + (size_t)l * 4096 * 1024, nullptr, ffbf, b1 + l * FFD, 4096, 1024, 1024, 16);
    k_gemm4<4><<<dim3(128, 4), B, 0, stream>>>(
        ffbf, w2T + (size_t)l * 1024 * 4096, slabs, nullptr, nullptr, 1024, 4096, 1024, 16);
    const float* ng = (l < 3) ? (attn_ng + (l + 1) * DM) : fin_g;
    const float* nb = (l < 3) ? (attn_nb + (l + 1) * DM) : fin_b;
    k_redadd_ln<<<SEQ, B, 0, stream>>>(h, slabs, b2 + l * DM, ng, nb, ybf);
  }

  k_gemm4<1><<<dim3(4000), B, 0, stream>>>(ybf, wlogT, out, nullptr, b_logit, NV, 1024, 1024, 16);
}